// Round 5
// baseline (1191.507 us; speedup 1.0000x reference)
//
#include <hip/hip_runtime.h>

// EPD GNN, factorized message passing.
// r5: GEMMs on matrix cores via split-bf16 (a=ah+al, 3 MFMAs: ah*bh+ah*bl+al*bh),
// fp32 accumulate -> ~2^-16 effective input precision. Weights packed once/call
// into MFMA-B layout Wp[n][k] (hi/lo bf16). A tile staged to LDS as bf16 hi/lo.
// 64-row tiles, 782 blocks. GEMMs are then HBM-bound (~51-77MB/dispatch).

#define NN 50000
#define EE 400000
#define GG 8
#define NBLK 196    // ceil(NN/256)
#define GB64 782    // ceil(NN/64)

typedef __attribute__((ext_vector_type(8))) short short8;
typedef __attribute__((ext_vector_type(4))) float floatx4;

__device__ __forceinline__ unsigned short f2bf(float x) {
    unsigned u = __float_as_uint(x);
    u += 0x7FFF + ((u >> 16) & 1);
    return (unsigned short)(u >> 16);
}
__device__ __forceinline__ float bf2f(unsigned short h) {
    return __uint_as_float(((unsigned)h) << 16);
}

// ---------------- CSR build ----------------
__global__ void k_count(const int* __restrict__ ei, int* __restrict__ deg) {
    int i = blockIdx.x * 256 + threadIdx.x;
    if (i < EE) atomicAdd(&deg[ei[EE + i]], 1);
}

__global__ __launch_bounds__(256) void k_scan1(const int* __restrict__ deg, int* __restrict__ ex,
                                               int* __restrict__ blksum) {
    __shared__ int s[256];
    const int t = threadIdx.x;
    int i = blockIdx.x * 256 + t;
    int v = (i < NN) ? deg[i] : 0;
    s[t] = v;
    __syncthreads();
    for (int off = 1; off < 256; off <<= 1) {
        int x = (t >= off) ? s[t - off] : 0;
        __syncthreads();
        s[t] += x;
        __syncthreads();
    }
    if (i < NN) ex[i] = s[t] - v;
    if (t == 255) blksum[blockIdx.x] = s[255];
}

__global__ __launch_bounds__(256) void k_scan2(int* __restrict__ blksum) {
    __shared__ int s[256];
    const int t = threadIdx.x;
    int v = (t < NBLK) ? blksum[t] : 0;
    s[t] = v;
    __syncthreads();
    for (int off = 1; off < 256; off <<= 1) {
        int x = (t >= off) ? s[t - off] : 0;
        __syncthreads();
        s[t] += x;
        __syncthreads();
    }
    if (t < NBLK) blksum[t] = s[t] - v;
}

__global__ void k_scan3(const int* __restrict__ ex, const int* __restrict__ blkoff,
                        int* __restrict__ row_ptr, int* __restrict__ cursor) {
    int i = blockIdx.x * 256 + threadIdx.x;
    if (i < NN) {
        int v = ex[i] + blkoff[blockIdx.x];
        row_ptr[i] = v;
        cursor[i] = v;
    }
    if (i == 0) row_ptr[NN] = EE;
}

__global__ void k_scatter(const int* __restrict__ ei, const float* __restrict__ ea,
                          int* __restrict__ cursor, int* __restrict__ src_sorted,
                          float4* __restrict__ ea_s) {
    int e = blockIdx.x * 256 + threadIdx.x;
    if (e >= EE) return;
    int s = ei[e], d = ei[EE + e];
    int p = atomicAdd(&cursor[d], 1);
    src_sorted[p] = s;
    ea_s[p] = make_float4(ea[3 * e], ea[3 * e + 1], ea[3 * e + 2], 0.f);
}

// ---------------- weight packing: W[KxN fp32, row-major] -> hi/lo bf16 [n][k] ----------------
__global__ __launch_bounds__(256) void k_pack_all(
    const float* __restrict__ We2, const float* __restrict__ Wm1,
    const float* __restrict__ Wm2, const float* __restrict__ Wu1,
    const float* __restrict__ Wu2, const float* __restrict__ Wd1,
    short* __restrict__ We2h, short* __restrict__ We2l,
    short* __restrict__ Wm1sh, short* __restrict__ Wm1sl,
    short* __restrict__ Wm1dh, short* __restrict__ Wm1dl,
    short* __restrict__ Wm2h, short* __restrict__ Wm2l,
    short* __restrict__ Wu1h, short* __restrict__ Wu1l,
    short* __restrict__ Wu2h, short* __restrict__ Wu2l,
    short* __restrict__ Wd1h, short* __restrict__ Wd1l) {
    int b = blockIdx.x;
    const float* W;
    short *hi, *lo;
    int K, local;
    if (b < 384) {
        int id = b >> 6;
        local = (b & 63) * 256 + threadIdx.x;
        K = 128;
        switch (id) {
            case 0: W = We2; hi = We2h; lo = We2l; break;
            case 1: W = Wm1; hi = Wm1sh; lo = Wm1sl; break;
            case 2: W = Wm1 + 16384; hi = Wm1dh; lo = Wm1dl; break;
            case 3: W = Wm2; hi = Wm2h; lo = Wm2l; break;
            case 4: W = Wu2; hi = Wu2h; lo = Wu2l; break;
            default: W = Wd1; hi = Wd1h; lo = Wd1l; break;
        }
    } else {
        W = Wu1; hi = Wu1h; lo = Wu1l; K = 256;
        local = (b - 384) * 256 + threadIdx.x;
    }
    int k = local >> 7, n = local & 127;
    float w = W[local];
    unsigned short h = f2bf(w);
    hi[(size_t)n * K + k] = (short)h;
    lo[(size_t)n * K + k] = (short)f2bf(w - bf2f(h));
}

// ---------------- encoder layer 1 (K=8) ----------------
__global__ __launch_bounds__(256) void k_enc1(const float* __restrict__ x, const float* __restrict__ xm,
                                              const float* __restrict__ We1, const float* __restrict__ be1,
                                              float* __restrict__ t, int n) {
    __shared__ float w[8][128];
    __shared__ float b[128];
    int tid = threadIdx.x;
    for (int i = tid; i < 1024; i += 256) w[i >> 7][i & 127] = We1[i];
    if (tid < 128) b[tid] = be1[tid];
    __syncthreads();
    const int c = tid & 127, rp = tid >> 7;
    const int row0 = blockIdx.x * 32;
    for (int i = 0; i < 16; ++i) {
        int r = row0 + rp * 16 + i;
        if (r >= n) break;
        float i0 = x[r * 5 + 0], i1 = x[r * 5 + 1], i2 = x[r * 5 + 2], i3 = x[r * 5 + 3], i4 = x[r * 5 + 4];
        float m0 = xm[r * 3 + 0], m1 = xm[r * 3 + 1], m2 = xm[r * 3 + 2];
        float s = b[c] + i0 * w[0][c] + i1 * w[1][c] + i2 * w[2][c] + i3 * w[3][c] + i4 * w[4][c]
                + m0 * w[5][c] + m1 * w[6][c] + m2 * w[7][c];
        t[(size_t)r * 128 + c] = fmaxf(s, 0.f);
    }
}

// ---------------- MFMA GEMM: 64x128 tile, split-bf16, W packed [n][Kw] ----------------
// out[M x 128] = op([A|A2][M x K] @ W).  K2: K=256 (A pass then A2 pass, Kw=256).
// STATS: per-graph column sums of output -> sum_h (pre-zeroed).
// DUAL: also out2 = A @ W2 + bias2.
#define LDA 136
template <bool RELU, bool ACCUM, bool BIAS, bool GTERM, bool K2, bool STATS, bool DUAL>
__global__ __launch_bounds__(256) void mgemm(const float* __restrict__ A, const float* __restrict__ A2,
                                             const short* __restrict__ Whi, const short* __restrict__ Wlo,
                                             const short* __restrict__ W2hi, const short* __restrict__ W2lo,
                                             const float* __restrict__ bias, const float* __restrict__ bias2,
                                             const float* __restrict__ gt, const int* __restrict__ batch,
                                             float* __restrict__ out, float* __restrict__ out2,
                                             float* __restrict__ sum_h, int M) {
    __shared__ short Ahi[64 * LDA];
    __shared__ short Alo[64 * LDA];
    const int tid = threadIdx.x;
    const int wave = tid >> 6, lane = tid & 63;
    const int m16 = lane & 15, quad = lane >> 4;
    const int row0 = blockIdx.x * 64;
    constexpr int Kw = K2 ? 256 : 128;

    floatx4 acc[8], acc2[8];
#pragma unroll
    for (int j = 0; j < 8; ++j) {
        acc[j] = (floatx4)0.f;
        if (DUAL) acc2[j] = (floatx4)0.f;
    }

    const int npass = K2 ? 2 : 1;
    for (int pass = 0; pass < npass; ++pass) {
        const float* Asrc = (pass == 0) ? A : A2;
        // stage 64x128 fp32 -> bf16 hi/lo in LDS
        {
            const int r = tid >> 2;
            const int c0 = (tid & 3) << 5;
            int rr = row0 + r;
            if (rr >= M) rr = M - 1;
            const float* ap = Asrc + (size_t)rr * 128 + c0;
            short* hp = &Ahi[r * LDA + c0];
            short* lp = &Alo[r * LDA + c0];
#pragma unroll
            for (int u = 0; u < 4; ++u) {
                float4 v0 = *(const float4*)(ap + u * 8);
                float4 v1 = *(const float4*)(ap + u * 8 + 4);
                float vv[8] = {v0.x, v0.y, v0.z, v0.w, v1.x, v1.y, v1.z, v1.w};
                short8 h8, l8;
#pragma unroll
                for (int j = 0; j < 8; ++j) {
                    unsigned short hh = f2bf(vv[j]);
                    h8[j] = (short)hh;
                    l8[j] = (short)f2bf(vv[j] - bf2f(hh));
                }
                *(short8*)(hp + u * 8) = h8;
                *(short8*)(lp + u * 8) = l8;
            }
        }
        __syncthreads();

        const int arow = (wave * 16 + m16) * LDA + quad * 8;
#pragma unroll
        for (int k0 = 0; k0 < 128; k0 += 32) {
            short8 ah = *(const short8*)&Ahi[arow + k0];
            short8 al = *(const short8*)&Alo[arow + k0];
            const int kglob = (K2 ? pass * 128 : 0) + k0 + quad * 8;
#pragma unroll
            for (int nt = 0; nt < 8; ++nt) {
                const size_t woff = (size_t)(nt * 16 + m16) * Kw + kglob;
                short8 bh = *(const short8*)(Whi + woff);
                short8 bl = *(const short8*)(Wlo + woff);
                acc[nt] = __builtin_amdgcn_mfma_f32_16x16x32_bf16(ah, bh, acc[nt], 0, 0, 0);
                acc[nt] = __builtin_amdgcn_mfma_f32_16x16x32_bf16(ah, bl, acc[nt], 0, 0, 0);
                acc[nt] = __builtin_amdgcn_mfma_f32_16x16x32_bf16(al, bh, acc[nt], 0, 0, 0);
                if (DUAL) {
                    short8 ch = *(const short8*)(W2hi + woff);
                    short8 cl = *(const short8*)(W2lo + woff);
                    acc2[nt] = __builtin_amdgcn_mfma_f32_16x16x32_bf16(ah, ch, acc2[nt], 0, 0, 0);
                    acc2[nt] = __builtin_amdgcn_mfma_f32_16x16x32_bf16(ah, cl, acc2[nt], 0, 0, 0);
                    acc2[nt] = __builtin_amdgcn_mfma_f32_16x16x32_bf16(al, ch, acc2[nt], 0, 0, 0);
                }
            }
        }
        if (pass + 1 < npass) __syncthreads();
    }

    // epilogue: lane holds rows row0+wave*16+quad*4+i (i=0..3), cols nt*16+m16
    int gsl = 0;
    bool uni = true;
    if (STATS) {
        int rlo = (row0 < M) ? row0 : (M - 1);
        int rhi = (row0 + 63 < M) ? row0 + 63 : (M - 1);
        gsl = batch[rlo];
        uni = (gsl == batch[rhi]);
    }
    float colsum[8];
    if (STATS) {
#pragma unroll
        for (int j = 0; j < 8; ++j) colsum[j] = 0.f;
    }
#pragma unroll
    for (int nt = 0; nt < 8; ++nt) {
        const int col = nt * 16 + m16;
        const float bcol = BIAS ? bias[col] : 0.f;
        const float b2col = DUAL ? bias2[col] : 0.f;
#pragma unroll
        for (int i = 0; i < 4; ++i) {
            int r = row0 + wave * 16 + quad * 4 + i;
            if (r >= M) continue;
            size_t off = (size_t)r * 128 + col;
            float o = acc[nt][i] + bcol;
            if (GTERM) o += gt[batch[r] * 128 + col];
            if (ACCUM) o += out[off];
            if (RELU) o = fmaxf(o, 0.f);
            if (STATS) {
                if (uni) colsum[nt] += o;
                else atomicAdd(&sum_h[batch[r] * 128 + col], o);
            }
            out[off] = o;
            if (DUAL) out2[off] = acc2[nt][i] + b2col;
        }
    }
    if (STATS && uni) {
        float* ssum = (float*)Ahi;
        __syncthreads();
        if (tid < 128) ssum[tid] = 0.f;
        __syncthreads();
#pragma unroll
        for (int nt = 0; nt < 8; ++nt) {
            float v = colsum[nt];
            v += __shfl_xor(v, 16);
            v += __shfl_xor(v, 32);
            if (quad == 0) atomicAdd(&ssum[nt * 16 + m16], v);
        }
        __syncthreads();
        if (tid < 128) atomicAdd(&sum_h[gsl * 128 + tid], ssum[tid]);
    }
}

// ---------------- edge aggregation: one wave per destination node ----------------
__global__ __launch_bounds__(256) void k_edge_agg(const float* __restrict__ Ps, const float* __restrict__ Pd,
                                                  const int* __restrict__ row_ptr, const int* __restrict__ src_sorted,
                                                  const float4* __restrict__ ea_s, const float* __restrict__ Wm1,
                                                  float* __restrict__ accm) {
    const int lane = threadIdx.x & 63;
    const int d = blockIdx.x * 4 + (threadIdx.x >> 6);
    const int c = lane * 2;
    const float2 w0 = *(const float2*)&Wm1[256 * 128 + c];
    const float2 w1 = *(const float2*)&Wm1[257 * 128 + c];
    const float2 w2 = *(const float2*)&Wm1[258 * 128 + c];
    const float2 pd = *(const float2*)&Pd[(size_t)d * 128 + c];
    const int beg = row_ptr[d], end = row_ptr[d + 1];
    const float2 sv = *(const float2*)&Ps[(size_t)d * 128 + c];
    float ax = fmaxf(sv.x + pd.x, 0.f);
    float ay = fmaxf(sv.y + pd.y, 0.f);
    int k = beg;
    for (; k + 3 < end; k += 4) {
        int s0 = src_sorted[k], s1 = src_sorted[k + 1], s2 = src_sorted[k + 2], s3 = src_sorted[k + 3];
        float4 e0 = ea_s[k], e1 = ea_s[k + 1], e2 = ea_s[k + 2], e3 = ea_s[k + 3];
        float2 pa = *(const float2*)&Ps[(size_t)s0 * 128 + c];
        float2 pb = *(const float2*)&Ps[(size_t)s1 * 128 + c];
        float2 pc = *(const float2*)&Ps[(size_t)s2 * 128 + c];
        float2 pe = *(const float2*)&Ps[(size_t)s3 * 128 + c];
        ax += fmaxf(pa.x + pd.x + e0.x * w0.x + e0.y * w1.x + e0.z * w2.x, 0.f)
            + fmaxf(pb.x + pd.x + e1.x * w0.x + e1.y * w1.x + e1.z * w2.x, 0.f)
            + fmaxf(pc.x + pd.x + e2.x * w0.x + e2.y * w1.x + e2.z * w2.x, 0.f)
            + fmaxf(pe.x + pd.x + e3.x * w0.x + e3.y * w1.x + e3.z * w2.x, 0.f);
        ay += fmaxf(pa.y + pd.y + e0.x * w0.y + e0.y * w1.y + e0.z * w2.y, 0.f)
            + fmaxf(pb.y + pd.y + e1.x * w0.y + e1.y * w1.y + e1.z * w2.y, 0.f)
            + fmaxf(pc.y + pd.y + e2.x * w0.y + e2.y * w1.y + e2.z * w2.y, 0.f)
            + fmaxf(pe.y + pd.y + e3.x * w0.y + e3.y * w1.y + e3.z * w2.y, 0.f);
    }
    for (; k < end; ++k) {
        int s0 = src_sorted[k];
        float4 e0 = ea_s[k];
        float2 pa = *(const float2*)&Ps[(size_t)s0 * 128 + c];
        ax += fmaxf(pa.x + pd.x + e0.x * w0.x + e0.y * w1.x + e0.z * w2.x, 0.f);
        ay += fmaxf(pa.y + pd.y + e0.x * w0.y + e0.y * w1.y + e0.z * w2.y, 0.f);
    }
    float inv = 1.f / (float)(end - beg + 1);
    *(float2*)&accm[(size_t)d * 128 + c] = make_float2(ax * inv, ay * inv);
}

// ---------------- encoder per-graph stats (once) ----------------
__global__ __launch_bounds__(256) void k_stats_bc(const float* __restrict__ h, const float* __restrict__ xm,
                                                  const int* __restrict__ batch, float* __restrict__ sum_h,
                                                  float* __restrict__ sum_hbc, float* __restrict__ cnt_node,
                                                  float* __restrict__ cnt_bc) {
    __shared__ float sred[8][128];
    __shared__ float scn[8], scb[8];
    const int t = threadIdx.x;
    const int c4 = (t & 31) * 4;
    const int rsub = t >> 5;   // 0..7
    const int row0 = blockIdx.x * 64;
    int rlo = (row0 < NN) ? row0 : (NN - 1);
    int rhi = (row0 + 63 < NN) ? row0 + 63 : (NN - 1);
    const int gl = batch[rlo];
    const bool uni = (gl == batch[rhi]);
    float4 s = make_float4(0.f, 0.f, 0.f, 0.f), sb = make_float4(0.f, 0.f, 0.f, 0.f);
    float cn = 0.f, cb = 0.f;
#pragma unroll
    for (int ii = 0; ii < 8; ++ii) {
        int r = row0 + ii * 8 + rsub;
        if (r >= NN) continue;
        float4 v = *(const float4*)(h + (size_t)r * 128 + c4);
        float bc = xm[r * 3 + 2];
        if (uni) {
            s.x += v.x; s.y += v.y; s.z += v.z; s.w += v.w;
            sb.x += v.x * bc; sb.y += v.y * bc; sb.z += v.z * bc; sb.w += v.w * bc;
            if ((t & 31) == 0) { cn += 1.f; cb += bc; }
        } else {
            int g = batch[r];
            atomicAdd(&sum_h[g * 128 + c4 + 0], v.x);
            atomicAdd(&sum_h[g * 128 + c4 + 1], v.y);
            atomicAdd(&sum_h[g * 128 + c4 + 2], v.z);
            atomicAdd(&sum_h[g * 128 + c4 + 3], v.w);
            atomicAdd(&sum_hbc[g * 128 + c4 + 0], v.x * bc);
            atomicAdd(&sum_hbc[g * 128 + c4 + 1], v.y * bc);
            atomicAdd(&sum_hbc[g * 128 + c4 + 2], v.z * bc);
            atomicAdd(&sum_hbc[g * 128 + c4 + 3], v.w * bc);
            if ((t & 31) == 0) {
                atomicAdd(&cnt_node[g], 1.f);
                atomicAdd(&cnt_bc[g], bc);
            }
        }
    }
    if (!uni) return;
    *(float4*)&sred[rsub][c4] = s;
    __syncthreads();
    if (t < 128) {
        float tot = 0.f;
#pragma unroll
        for (int q = 0; q < 8; ++q) tot += sred[q][t];
        atomicAdd(&sum_h[gl * 128 + t], tot);
    }
    __syncthreads();
    *(float4*)&sred[rsub][c4] = sb;
    if ((t & 31) == 0) { scn[rsub] = cn; scb[rsub] = cb; }
    __syncthreads();
    if (t < 128) {
        float tot = 0.f;
#pragma unroll
        for (int q = 0; q < 8; ++q) tot += sred[q][t];
        atomicAdd(&sum_hbc[gl * 128 + t], tot);
    }
    if (t == 0) {
        float a = 0.f, b = 0.f;
#pragma unroll
        for (int q = 0; q < 8; ++q) { a += scn[q]; b += scb[q]; }
        atomicAdd(&cnt_node[gl], a);
        atomicAdd(&cnt_bc[gl], b);
    }
}

// gterm[g] = mean_h[g] @ Wu1[256:384] + mean_hbc[g] @ Wu1[384:512]
__global__ __launch_bounds__(128) void k_gterm(const float* __restrict__ sum_h, const float* __restrict__ sum_hbc,
                                               const float* __restrict__ cnt_node, const float* __restrict__ cnt_bc,
                                               const float* __restrict__ Wu1, float* __restrict__ gt) {
    const int g = blockIdx.x;
    const int c = threadIdx.x;
    __shared__ float sg[128], sb[128];
    const float invn = 1.f / fmaxf(cnt_node[g], 1.f);
    const float invb = 1.f / fmaxf(cnt_bc[g], 1.f);
    sg[c] = sum_h[g * 128 + c] * invn;
    sb[c] = sum_hbc[g * 128 + c] * invb;
    __syncthreads();
    float s = 0.f;
    for (int k = 0; k < 128; ++k) s += sg[k] * Wu1[(256 + k) * 128 + c];
    for (int k = 0; k < 128; ++k) s += sb[k] * Wu1[(384 + k) * 128 + c];
    gt[g * 128 + c] = s;
}

// ---------------- decoder layer 2 (128 -> 3), one wave per row ----------------
__global__ __launch_bounds__(256) void k_dec2(const float* __restrict__ t, const float* __restrict__ Wd2,
                                              const float* __restrict__ bd2, float* __restrict__ out, int n) {
    const int lane = threadIdx.x & 63;
    const int r = blockIdx.x * 4 + (threadIdx.x >> 6);
    if (r >= n) return;
    float p0 = 0.f, p1 = 0.f, p2 = 0.f;
    for (int k = lane; k < 128; k += 64) {
        float tv = t[(size_t)r * 128 + k];
        p0 += tv * Wd2[k * 3 + 0];
        p1 += tv * Wd2[k * 3 + 1];
        p2 += tv * Wd2[k * 3 + 2];
    }
    for (int off = 32; off; off >>= 1) {
        p0 += __shfl_down(p0, off);
        p1 += __shfl_down(p1, off);
        p2 += __shfl_down(p2, off);
    }
    if (lane == 0) {
        out[r * 3 + 0] = p0 + bd2[0];
        out[r * 3 + 1] = p1 + bd2[1];
        out[r * 3 + 2] = p2 + bd2[2];
    }
}

extern "C" void kernel_launch(void* const* d_in, const int* in_sizes, int n_in,
                              void* d_out, int out_size, void* d_ws, size_t ws_size,
                              hipStream_t stream) {
    const float* x = (const float*)d_in[0];
    const float* x_mask = (const float*)d_in[1];
    const float* edge_attr = (const float*)d_in[2];
    const float* W_e1 = (const float*)d_in[4];
    const float* b_e1 = (const float*)d_in[5];
    const float* W_e2 = (const float*)d_in[6];
    const float* b_e2 = (const float*)d_in[7];
    const float* W_m1 = (const float*)d_in[8];
    const float* b_m1 = (const float*)d_in[9];
    const float* W_m2 = (const float*)d_in[10];
    const float* b_m2 = (const float*)d_in[11];
    const float* W_u1 = (const float*)d_in[12];
    const float* b_u1 = (const float*)d_in[13];
    const float* W_u2 = (const float*)d_in[14];
    const float* b_u2 = (const float*)d_in[15];
    const float* W_d1 = (const float*)d_in[16];
    const float* b_d1 = (const float*)d_in[17];
    const float* W_d2 = (const float*)d_in[18];
    const float* b_d2 = (const float*)d_in[19];
    const int* edge_index = (const int*)d_in[20];
    const int* batch = (const int*)d_in[21];
    float* out = (float*)d_out;

    char* wp = (char*)d_ws;
    auto carve = [&](size_t bytes) {
        char* r = wp;
        wp += (bytes + 255) & ~(size_t)255;
        return r;
    };
    float* h = (float*)carve(sizeof(float) * (size_t)NN * 128);
    float* Ps = (float*)carve(sizeof(float) * (size_t)NN * 128);
    float* Pd = (float*)carve(sizeof(float) * (size_t)NN * 128);
    float* accm = (float*)carve(sizeof(float) * (size_t)NN * 128);
    float4* ea_s = (float4*)carve(sizeof(float4) * (size_t)EE);
    float* stats = (float*)carve(sizeof(float) * 4096);
    float* sum_h = stats;             // 1024
    float* sum_hbc = stats + 1024;    // 1024
    float* cnt_node = stats + 2048;   // 8
    float* cnt_bc = stats + 2056;     // 8
    float* gterm = stats + 2304;      // 1024
    int* deg = (int*)carve(sizeof(int) * NN);
    int* row_ptr = (int*)carve(sizeof(int) * (NN + 1));
    int* cursor = (int*)carve(sizeof(int) * NN);
    int* src_sorted = (int*)carve(sizeof(int) * EE);
    int* exbuf = (int*)carve(sizeof(int) * NN);
    int* blksum = (int*)carve(sizeof(int) * 256);
    // packed weights (bf16 hi/lo, [n][k])
    short* We2h = (short*)carve(sizeof(short) * 16384);
    short* We2l = (short*)carve(sizeof(short) * 16384);
    short* Wm1sh = (short*)carve(sizeof(short) * 16384);
    short* Wm1sl = (short*)carve(sizeof(short) * 16384);
    short* Wm1dh = (short*)carve(sizeof(short) * 16384);
    short* Wm1dl = (short*)carve(sizeof(short) * 16384);
    short* Wm2h = (short*)carve(sizeof(short) * 16384);
    short* Wm2l = (short*)carve(sizeof(short) * 16384);
    short* Wu1h = (short*)carve(sizeof(short) * 32768);
    short* Wu1l = (short*)carve(sizeof(short) * 32768);
    short* Wu2h = (short*)carve(sizeof(short) * 16384);
    short* Wu2l = (short*)carve(sizeof(short) * 16384);
    short* Wd1h = (short*)carve(sizeof(short) * 16384);
    short* Wd1l = (short*)carve(sizeof(short) * 16384);

    const dim3 b256(256);
    const int gE256 = (EE + 255) / 256;

    hipMemsetAsync(deg, 0, sizeof(int) * NN, stream);
    hipMemsetAsync(stats, 0, sizeof(float) * 2064, stream);
    // pack all weights to bf16 hi/lo MFMA-B layout
    k_pack_all<<<512, b256, 0, stream>>>(W_e2, W_m1, W_m2, W_u1, W_u2, W_d1,
                                         We2h, We2l, Wm1sh, Wm1sl, Wm1dh, Wm1dl,
                                         Wm2h, Wm2l, Wu1h, Wu1l, Wu2h, Wu2l, Wd1h, Wd1l);
    // CSR
    k_count<<<gE256, b256, 0, stream>>>(edge_index, deg);
    k_scan1<<<NBLK, b256, 0, stream>>>(deg, exbuf, blksum);
    k_scan2<<<1, b256, 0, stream>>>(blksum);
    k_scan3<<<NBLK, b256, 0, stream>>>(exbuf, blksum, row_ptr, cursor);
    k_scatter<<<gE256, b256, 0, stream>>>(edge_index, edge_attr, cursor, src_sorted, ea_s);
    // encoder
    k_enc1<<<(NN + 31) / 32, b256, 0, stream>>>(x, x_mask, W_e1, b_e1, accm, NN);
    mgemm<false, false, true, false, false, false, false><<<GB64, b256, 0, stream>>>(
        accm, nullptr, We2h, We2l, nullptr, nullptr, b_e2, nullptr, nullptr, nullptr, h, nullptr, nullptr, NN);
    // per-graph stats (once)
    k_stats_bc<<<GB64, b256, 0, stream>>>(h, x_mask, batch, sum_h, sum_hbc, cnt_node, cnt_bc);

    for (int rep = 0; rep < 3; ++rep) {
        k_gterm<<<GG, 128, 0, stream>>>(sum_h, sum_hbc, cnt_node, cnt_bc, W_u1, gterm);
        // Ps = h@W_m1[src]; Pd = h@W_m1[dst] + b_m1  (one pass over h)
        mgemm<false, false, false, false, false, false, true><<<GB64, b256, 0, stream>>>(
            h, nullptr, Wm1sh, Wm1sl, Wm1dh, Wm1dl, nullptr, b_m1, nullptr, nullptr, Ps, Pd, nullptr, NN);
        k_edge_agg<<<NN / 4, b256, 0, stream>>>(Ps, Pd, row_ptr, src_sorted, ea_s, W_m1, accm);
        // agg = accm @ W_m2 + b_m2 -> Ps
        mgemm<false, false, true, false, false, false, false><<<GB64, b256, 0, stream>>>(
            accm, nullptr, Wm2h, Wm2l, nullptr, nullptr, b_m2, nullptr, nullptr, nullptr, Ps, nullptr, nullptr, NN);
        // pre = relu([h|agg] @ Wu1[0:256] + gterm[batch] + b_u1) -> Pd
        mgemm<true, false, true, true, true, false, false><<<GB64, b256, 0, stream>>>(
            h, Ps, Wu1h, Wu1l, nullptr, nullptr, b_u1, nullptr, gterm, batch, Pd, nullptr, nullptr, NN);
        // h += pre @ Wu2 + bu2 (+ fused per-graph column sums for next rep)
        if (rep < 2) {
            hipMemsetAsync(sum_h, 0, sizeof(float) * 1024, stream);
            mgemm<false, true, true, false, false, true, false><<<GB64, b256, 0, stream>>>(
                Pd, nullptr, Wu2h, Wu2l, nullptr, nullptr, b_u2, nullptr, nullptr, batch, h, nullptr, sum_h, NN);
        } else {
            mgemm<false, true, true, false, false, false, false><<<GB64, b256, 0, stream>>>(
                Pd, nullptr, Wu2h, Wu2l, nullptr, nullptr, b_u2, nullptr, nullptr, batch, h, nullptr, nullptr, NN);
        }
    }
    // decoder
    mgemm<true, false, true, false, false, false, false><<<GB64, b256, 0, stream>>>(
        h, nullptr, Wd1h, Wd1l, nullptr, nullptr, b_d1, nullptr, nullptr, nullptr, accm, nullptr, nullptr, NN);
    k_dec2<<<NN / 4, b256, 0, stream>>>(accm, W_d2, b_d2, out, NN);
}

// Round 6
// 769.838 us; speedup vs baseline: 1.5477x; 1.5477x over previous
//
#include <hip/hip_runtime.h>

// EPD GNN, factorized message passing.
// r6: split-bf16 MFMA GEMM (a=ah+al, 3 MFMAs/frag). W packed hi/lo [n][k] once
// per call; mgemm stages W into LDS in k-windows (coalesced), A-fragments read
// DIRECTLY from global (one 32B row-segment per lane per 24 MFMAs) and converted
// in registers. Non-DUAL: 64-k window, 36KB LDS, 4 blk/CU. DUAL: 32-k, 41KB, 3.
// GEMMs should be HBM-bound (~51-77MB/dispatch -> ~8-12us).

#define NN 50000
#define EE 400000
#define GG 8
#define NBLK 196    // ceil(NN/256)
#define GB64 782    // ceil(NN/64)

typedef __attribute__((ext_vector_type(8))) short short8;
typedef __attribute__((ext_vector_type(4))) float floatx4;

__device__ __forceinline__ unsigned short f2bf(float x) {
    unsigned u = __float_as_uint(x);
    u += 0x7FFF + ((u >> 16) & 1);
    return (unsigned short)(u >> 16);
}
__device__ __forceinline__ float bf2f(unsigned short h) {
    return __uint_as_float(((unsigned)h) << 16);
}

// ---------------- CSR build ----------------
__global__ void k_count(const int* __restrict__ ei, int* __restrict__ deg) {
    int i = blockIdx.x * 256 + threadIdx.x;
    if (i < EE) atomicAdd(&deg[ei[EE + i]], 1);
}

__global__ __launch_bounds__(256) void k_scan1(const int* __restrict__ deg, int* __restrict__ ex,
                                               int* __restrict__ blksum) {
    __shared__ int s[256];
    const int t = threadIdx.x;
    int i = blockIdx.x * 256 + t;
    int v = (i < NN) ? deg[i] : 0;
    s[t] = v;
    __syncthreads();
    for (int off = 1; off < 256; off <<= 1) {
        int x = (t >= off) ? s[t - off] : 0;
        __syncthreads();
        s[t] += x;
        __syncthreads();
    }
    if (i < NN) ex[i] = s[t] - v;
    if (t == 255) blksum[blockIdx.x] = s[255];
}

__global__ __launch_bounds__(256) void k_scan2(int* __restrict__ blksum) {
    __shared__ int s[256];
    const int t = threadIdx.x;
    int v = (t < NBLK) ? blksum[t] : 0;
    s[t] = v;
    __syncthreads();
    for (int off = 1; off < 256; off <<= 1) {
        int x = (t >= off) ? s[t - off] : 0;
        __syncthreads();
        s[t] += x;
        __syncthreads();
    }
    if (t < NBLK) blksum[t] = s[t] - v;
}

__global__ void k_scan3(const int* __restrict__ ex, const int* __restrict__ blkoff,
                        int* __restrict__ row_ptr, int* __restrict__ cursor) {
    int i = blockIdx.x * 256 + threadIdx.x;
    if (i < NN) {
        int v = ex[i] + blkoff[blockIdx.x];
        row_ptr[i] = v;
        cursor[i] = v;
    }
    if (i == 0) row_ptr[NN] = EE;
}

__global__ void k_scatter(const int* __restrict__ ei, const float* __restrict__ ea,
                          int* __restrict__ cursor, int* __restrict__ src_sorted,
                          float4* __restrict__ ea_s) {
    int e = blockIdx.x * 256 + threadIdx.x;
    if (e >= EE) return;
    int s = ei[e], d = ei[EE + e];
    int p = atomicAdd(&cursor[d], 1);
    src_sorted[p] = s;
    ea_s[p] = make_float4(ea[3 * e], ea[3 * e + 1], ea[3 * e + 2], 0.f);
}

// ---------------- weight packing: W[KxN fp32, row-major] -> hi/lo bf16 [n][k] ----------------
__global__ __launch_bounds__(256) void k_pack_all(
    const float* __restrict__ We2, const float* __restrict__ Wm1,
    const float* __restrict__ Wm2, const float* __restrict__ Wu1,
    const float* __restrict__ Wu2, const float* __restrict__ Wd1,
    short* __restrict__ We2h, short* __restrict__ We2l,
    short* __restrict__ Wm1sh, short* __restrict__ Wm1sl,
    short* __restrict__ Wm1dh, short* __restrict__ Wm1dl,
    short* __restrict__ Wm2h, short* __restrict__ Wm2l,
    short* __restrict__ Wu1h, short* __restrict__ Wu1l,
    short* __restrict__ Wu2h, short* __restrict__ Wu2l,
    short* __restrict__ Wd1h, short* __restrict__ Wd1l) {
    int b = blockIdx.x;
    const float* W;
    short *hi, *lo;
    int K, local;
    if (b < 384) {
        int id = b >> 6;
        local = (b & 63) * 256 + threadIdx.x;
        K = 128;
        switch (id) {
            case 0: W = We2; hi = We2h; lo = We2l; break;
            case 1: W = Wm1; hi = Wm1sh; lo = Wm1sl; break;
            case 2: W = Wm1 + 16384; hi = Wm1dh; lo = Wm1dl; break;
            case 3: W = Wm2; hi = Wm2h; lo = Wm2l; break;
            case 4: W = Wu2; hi = Wu2h; lo = Wu2l; break;
            default: W = Wd1; hi = Wd1h; lo = Wd1l; break;
        }
    } else {
        W = Wu1; hi = Wu1h; lo = Wu1l; K = 256;
        local = (b - 384) * 256 + threadIdx.x;
    }
    int k = local >> 7, n = local & 127;
    float w = W[local];
    unsigned short h = f2bf(w);
    hi[(size_t)n * K + k] = (short)h;
    lo[(size_t)n * K + k] = (short)f2bf(w - bf2f(h));
}

// ---------------- encoder layer 1 (K=8) ----------------
__global__ __launch_bounds__(256) void k_enc1(const float* __restrict__ x, const float* __restrict__ xm,
                                              const float* __restrict__ We1, const float* __restrict__ be1,
                                              float* __restrict__ t, int n) {
    __shared__ float w[8][128];
    __shared__ float b[128];
    int tid = threadIdx.x;
    for (int i = tid; i < 1024; i += 256) w[i >> 7][i & 127] = We1[i];
    if (tid < 128) b[tid] = be1[tid];
    __syncthreads();
    const int c = tid & 127, rp = tid >> 7;
    const int row0 = blockIdx.x * 32;
    for (int i = 0; i < 16; ++i) {
        int r = row0 + rp * 16 + i;
        if (r >= n) break;
        float i0 = x[r * 5 + 0], i1 = x[r * 5 + 1], i2 = x[r * 5 + 2], i3 = x[r * 5 + 3], i4 = x[r * 5 + 4];
        float m0 = xm[r * 3 + 0], m1 = xm[r * 3 + 1], m2 = xm[r * 3 + 2];
        float s = b[c] + i0 * w[0][c] + i1 * w[1][c] + i2 * w[2][c] + i3 * w[3][c] + i4 * w[4][c]
                + m0 * w[5][c] + m1 * w[6][c] + m2 * w[7][c];
        t[(size_t)r * 128 + c] = fmaxf(s, 0.f);
    }
}

__device__ __forceinline__ void cvt8(const float* v, short8& hi, short8& lo) {
#pragma unroll
    for (int j = 0; j < 8; ++j) {
        unsigned short h = f2bf(v[j]);
        hi[j] = (short)h;
        lo[j] = (short)f2bf(v[j] - bf2f(h));
    }
}

// ---------------- MFMA GEMM: 64x128 tile, split-bf16 ----------------
// W hi/lo staged to LDS in k-windows; A-fragments direct from global per lane.
// out[M x 128] = op([A|A2][M x K] @ W). K2: K=256. STATS: per-graph col sums.
// DUAL: also out2 = A @ W2 + bias2.
template <bool RELU, bool ACCUM, bool BIAS, bool GTERM, bool K2, bool STATS, bool DUAL>
__global__ __launch_bounds__(256) void mgemm(const float* __restrict__ A, const float* __restrict__ A2,
                                             const short* __restrict__ Whi, const short* __restrict__ Wlo,
                                             const short* __restrict__ W2hi, const short* __restrict__ W2lo,
                                             const float* __restrict__ bias, const float* __restrict__ bias2,
                                             const float* __restrict__ gt, const int* __restrict__ batch,
                                             float* __restrict__ out, float* __restrict__ out2,
                                             float* __restrict__ sum_h, int M) {
    constexpr int KWIN = DUAL ? 32 : 64;   // k-window staged in LDS
    constexpr int LDW = KWIN + 8;          // padded row (shorts); 16B-aligned rows
    constexpr int NKH = 128 / KWIN;
    constexpr int NK0 = KWIN / 32;
    constexpr int WBUF = 128 * LDW;
    constexpr int NSET = DUAL ? 4 : 2;
    constexpr int NCH = (128 * KWIN / 8) / 256;   // b128 chunks per buffer per thread
    __shared__ short sW[NSET * WBUF];
    short* sWh = sW;
    short* sWl = sW + WBUF;
    short* sW2h = sW + 2 * WBUF;
    short* sW2l = sW + 3 * WBUF;

    const int tid = threadIdx.x;
    const int wave = tid >> 6, lane = tid & 63;
    const int m16 = lane & 15, quad = lane >> 4;
    const int row0 = blockIdx.x * 64;
    constexpr int Kw = K2 ? 256 : 128;

    int arow = row0 + wave * 16 + m16;
    if (arow >= M) arow = M - 1;

    floatx4 acc[8], acc2[8];
#pragma unroll
    for (int j = 0; j < 8; ++j) {
        acc[j] = (floatx4)0.f;
        if (DUAL) acc2[j] = (floatx4)0.f;
    }

    const int npass = K2 ? 2 : 1;
    for (int pass = 0; pass < npass; ++pass) {
        const float* Arow = ((pass == 0) ? A : A2) + (size_t)arow * 128;
#pragma unroll
        for (int kh = 0; kh < NKH; ++kh) {
            // issue A loads for this window early (independent of LDS)
            float af[NK0][8];
#pragma unroll
            for (int k0i = 0; k0i < NK0; ++k0i) {
                int acol = kh * KWIN + k0i * 32 + quad * 8;
                *(float4*)&af[k0i][0] = *(const float4*)(Arow + acol);
                *(float4*)&af[k0i][4] = *(const float4*)(Arow + acol + 4);
            }
            __syncthreads();   // previous window's reads done
            {
                const int kbase = pass * 128 + kh * KWIN;
#pragma unroll
                for (int i = 0; i < NCH; ++i) {
                    int c = tid + i * 256;
                    int n = c / (KWIN / 8);
                    int ks = (c % (KWIN / 8)) * 8;
                    size_t g = (size_t)n * Kw + kbase + ks;
                    int l = n * LDW + ks;
                    *(short8*)&sWh[l] = *(const short8*)(Whi + g);
                    *(short8*)&sWl[l] = *(const short8*)(Wlo + g);
                    if (DUAL) {
                        *(short8*)&sW2h[l] = *(const short8*)(W2hi + g);
                        *(short8*)&sW2l[l] = *(const short8*)(W2lo + g);
                    }
                }
            }
            __syncthreads();
#pragma unroll
            for (int k0i = 0; k0i < NK0; ++k0i) {
                short8 ah, al;
                cvt8(af[k0i], ah, al);
                const int kof = k0i * 32 + quad * 8;
#pragma unroll
                for (int nt = 0; nt < 8; ++nt) {
                    const int woff = (nt * 16 + m16) * LDW + kof;
                    short8 bh = *(const short8*)&sWh[woff];
                    short8 bl = *(const short8*)&sWl[woff];
                    acc[nt] = __builtin_amdgcn_mfma_f32_16x16x32_bf16(ah, bh, acc[nt], 0, 0, 0);
                    acc[nt] = __builtin_amdgcn_mfma_f32_16x16x32_bf16(ah, bl, acc[nt], 0, 0, 0);
                    acc[nt] = __builtin_amdgcn_mfma_f32_16x16x32_bf16(al, bh, acc[nt], 0, 0, 0);
                    if (DUAL) {
                        short8 ch = *(const short8*)&sW2h[woff];
                        short8 cl = *(const short8*)&sW2l[woff];
                        acc2[nt] = __builtin_amdgcn_mfma_f32_16x16x32_bf16(ah, ch, acc2[nt], 0, 0, 0);
                        acc2[nt] = __builtin_amdgcn_mfma_f32_16x16x32_bf16(ah, cl, acc2[nt], 0, 0, 0);
                        acc2[nt] = __builtin_amdgcn_mfma_f32_16x16x32_bf16(al, ch, acc2[nt], 0, 0, 0);
                    }
                }
            }
        }
    }

    // epilogue: lane holds rows row0+wave*16+quad*4+i (i=0..3), cols nt*16+m16
    int gsl = 0;
    bool uni = true;
    if (STATS) {
        int rlo = (row0 < M) ? row0 : (M - 1);
        int rhi = (row0 + 63 < M) ? row0 + 63 : (M - 1);
        gsl = batch[rlo];
        uni = (gsl == batch[rhi]);
    }
    float colsum[8];
    if (STATS) {
#pragma unroll
        for (int j = 0; j < 8; ++j) colsum[j] = 0.f;
    }
#pragma unroll
    for (int nt = 0; nt < 8; ++nt) {
        const int col = nt * 16 + m16;
        const float bcol = BIAS ? bias[col] : 0.f;
        const float b2col = DUAL ? bias2[col] : 0.f;
#pragma unroll
        for (int i = 0; i < 4; ++i) {
            int r = row0 + wave * 16 + quad * 4 + i;
            if (r >= M) continue;
            size_t off = (size_t)r * 128 + col;
            float o = acc[nt][i] + bcol;
            if (GTERM) o += gt[batch[r] * 128 + col];
            if (ACCUM) o += out[off];
            if (RELU) o = fmaxf(o, 0.f);
            if (STATS) {
                if (uni) colsum[nt] += o;
                else atomicAdd(&sum_h[batch[r] * 128 + col], o);
            }
            out[off] = o;
            if (DUAL) out2[off] = acc2[nt][i] + b2col;
        }
    }
    if (STATS && uni) {
        float* ssum = (float*)sW;
        __syncthreads();
        if (tid < 128) ssum[tid] = 0.f;
        __syncthreads();
#pragma unroll
        for (int nt = 0; nt < 8; ++nt) {
            float v = colsum[nt];
            v += __shfl_xor(v, 16);
            v += __shfl_xor(v, 32);
            if (quad == 0) atomicAdd(&ssum[nt * 16 + m16], v);
        }
        __syncthreads();
        if (tid < 128) atomicAdd(&sum_h[gsl * 128 + tid], ssum[tid]);
    }
}

// ---------------- edge aggregation: one wave per destination node ----------------
__global__ __launch_bounds__(256) void k_edge_agg(const float* __restrict__ Ps, const float* __restrict__ Pd,
                                                  const int* __restrict__ row_ptr, const int* __restrict__ src_sorted,
                                                  const float4* __restrict__ ea_s, const float* __restrict__ Wm1,
                                                  float* __restrict__ accm) {
    const int lane = threadIdx.x & 63;
    const int d = blockIdx.x * 4 + (threadIdx.x >> 6);
    const int c = lane * 2;
    const float2 w0 = *(const float2*)&Wm1[256 * 128 + c];
    const float2 w1 = *(const float2*)&Wm1[257 * 128 + c];
    const float2 w2 = *(const float2*)&Wm1[258 * 128 + c];
    const float2 pd = *(const float2*)&Pd[(size_t)d * 128 + c];
    const int beg = row_ptr[d], end = row_ptr[d + 1];
    const float2 sv = *(const float2*)&Ps[(size_t)d * 128 + c];
    float ax = fmaxf(sv.x + pd.x, 0.f);
    float ay = fmaxf(sv.y + pd.y, 0.f);
    int k = beg;
    for (; k + 3 < end; k += 4) {
        int s0 = src_sorted[k], s1 = src_sorted[k + 1], s2 = src_sorted[k + 2], s3 = src_sorted[k + 3];
        float4 e0 = ea_s[k], e1 = ea_s[k + 1], e2 = ea_s[k + 2], e3 = ea_s[k + 3];
        float2 pa = *(const float2*)&Ps[(size_t)s0 * 128 + c];
        float2 pb = *(const float2*)&Ps[(size_t)s1 * 128 + c];
        float2 pc = *(const float2*)&Ps[(size_t)s2 * 128 + c];
        float2 pe = *(const float2*)&Ps[(size_t)s3 * 128 + c];
        ax += fmaxf(pa.x + pd.x + e0.x * w0.x + e0.y * w1.x + e0.z * w2.x, 0.f)
            + fmaxf(pb.x + pd.x + e1.x * w0.x + e1.y * w1.x + e1.z * w2.x, 0.f)
            + fmaxf(pc.x + pd.x + e2.x * w0.x + e2.y * w1.x + e2.z * w2.x, 0.f)
            + fmaxf(pe.x + pd.x + e3.x * w0.x + e3.y * w1.x + e3.z * w2.x, 0.f);
        ay += fmaxf(pa.y + pd.y + e0.x * w0.y + e0.y * w1.y + e0.z * w2.y, 0.f)
            + fmaxf(pb.y + pd.y + e1.x * w0.y + e1.y * w1.y + e1.z * w2.y, 0.f)
            + fmaxf(pc.y + pd.y + e2.x * w0.y + e2.y * w1.y + e2.z * w2.y, 0.f)
            + fmaxf(pe.y + pd.y + e3.x * w0.y + e3.y * w1.y + e3.z * w2.y, 0.f);
    }
    for (; k < end; ++k) {
        int s0 = src_sorted[k];
        float4 e0 = ea_s[k];
        float2 pa = *(const float2*)&Ps[(size_t)s0 * 128 + c];
        ax += fmaxf(pa.x + pd.x + e0.x * w0.x + e0.y * w1.x + e0.z * w2.x, 0.f);
        ay += fmaxf(pa.y + pd.y + e0.x * w0.y + e0.y * w1.y + e0.z * w2.y, 0.f);
    }
    float inv = 1.f / (float)(end - beg + 1);
    *(float2*)&accm[(size_t)d * 128 + c] = make_float2(ax * inv, ay * inv);
}

// ---------------- encoder per-graph stats (once) ----------------
__global__ __launch_bounds__(256) void k_stats_bc(const float* __restrict__ h, const float* __restrict__ xm,
                                                  const int* __restrict__ batch, float* __restrict__ sum_h,
                                                  float* __restrict__ sum_hbc, float* __restrict__ cnt_node,
                                                  float* __restrict__ cnt_bc) {
    __shared__ float sred[8][128];
    __shared__ float scn[8], scb[8];
    const int t = threadIdx.x;
    const int c4 = (t & 31) * 4;
    const int rsub = t >> 5;   // 0..7
    const int row0 = blockIdx.x * 64;
    int rlo = (row0 < NN) ? row0 : (NN - 1);
    int rhi = (row0 + 63 < NN) ? row0 + 63 : (NN - 1);
    const int gl = batch[rlo];
    const bool uni = (gl == batch[rhi]);
    float4 s = make_float4(0.f, 0.f, 0.f, 0.f), sb = make_float4(0.f, 0.f, 0.f, 0.f);
    float cn = 0.f, cb = 0.f;
#pragma unroll
    for (int ii = 0; ii < 8; ++ii) {
        int r = row0 + ii * 8 + rsub;
        if (r >= NN) continue;
        float4 v = *(const float4*)(h + (size_t)r * 128 + c4);
        float bc = xm[r * 3 + 2];
        if (uni) {
            s.x += v.x; s.y += v.y; s.z += v.z; s.w += v.w;
            sb.x += v.x * bc; sb.y += v.y * bc; sb.z += v.z * bc; sb.w += v.w * bc;
            if ((t & 31) == 0) { cn += 1.f; cb += bc; }
        } else {
            int g = batch[r];
            atomicAdd(&sum_h[g * 128 + c4 + 0], v.x);
            atomicAdd(&sum_h[g * 128 + c4 + 1], v.y);
            atomicAdd(&sum_h[g * 128 + c4 + 2], v.z);
            atomicAdd(&sum_h[g * 128 + c4 + 3], v.w);
            atomicAdd(&sum_hbc[g * 128 + c4 + 0], v.x * bc);
            atomicAdd(&sum_hbc[g * 128 + c4 + 1], v.y * bc);
            atomicAdd(&sum_hbc[g * 128 + c4 + 2], v.z * bc);
            atomicAdd(&sum_hbc[g * 128 + c4 + 3], v.w * bc);
            if ((t & 31) == 0) {
                atomicAdd(&cnt_node[g], 1.f);
                atomicAdd(&cnt_bc[g], bc);
            }
        }
    }
    if (!uni) return;
    *(float4*)&sred[rsub][c4] = s;
    __syncthreads();
    if (t < 128) {
        float tot = 0.f;
#pragma unroll
        for (int q = 0; q < 8; ++q) tot += sred[q][t];
        atomicAdd(&sum_h[gl * 128 + t], tot);
    }
    __syncthreads();
    *(float4*)&sred[rsub][c4] = sb;
    if ((t & 31) == 0) { scn[rsub] = cn; scb[rsub] = cb; }
    __syncthreads();
    if (t < 128) {
        float tot = 0.f;
#pragma unroll
        for (int q = 0; q < 8; ++q) tot += sred[q][t];
        atomicAdd(&sum_hbc[gl * 128 + t], tot);
    }
    if (t == 0) {
        float a = 0.f, b = 0.f;
#pragma unroll
        for (int q = 0; q < 8; ++q) { a += scn[q]; b += scb[q]; }
        atomicAdd(&cnt_node[gl], a);
        atomicAdd(&cnt_bc[gl], b);
    }
}

// gterm[g] = mean_h[g] @ Wu1[256:384] + mean_hbc[g] @ Wu1[384:512]
__global__ __launch_bounds__(128) void k_gterm(const float* __restrict__ sum_h, const float* __restrict__ sum_hbc,
                                               const float* __restrict__ cnt_node, const float* __restrict__ cnt_bc,
                                               const float* __restrict__ Wu1, float* __restrict__ gt) {
    const int g = blockIdx.x;
    const int c = threadIdx.x;
    __shared__ float sg[128], sb[128];
    const float invn = 1.f / fmaxf(cnt_node[g], 1.f);
    const float invb = 1.f / fmaxf(cnt_bc[g], 1.f);
    sg[c] = sum_h[g * 128 + c] * invn;
    sb[c] = sum_hbc[g * 128 + c] * invb;
    __syncthreads();
    float s = 0.f;
    for (int k = 0; k < 128; ++k) s += sg[k] * Wu1[(256 + k) * 128 + c];
    for (int k = 0; k < 128; ++k) s += sb[k] * Wu1[(384 + k) * 128 + c];
    gt[g * 128 + c] = s;
}

// ---------------- decoder layer 2 (128 -> 3), one wave per row ----------------
__global__ __launch_bounds__(256) void k_dec2(const float* __restrict__ t, const float* __restrict__ Wd2,
                                              const float* __restrict__ bd2, float* __restrict__ out, int n) {
    const int lane = threadIdx.x & 63;
    const int r = blockIdx.x * 4 + (threadIdx.x >> 6);
    if (r >= n) return;
    float p0 = 0.f, p1 = 0.f, p2 = 0.f;
    for (int k = lane; k < 128; k += 64) {
        float tv = t[(size_t)r * 128 + k];
        p0 += tv * Wd2[k * 3 + 0];
        p1 += tv * Wd2[k * 3 + 1];
        p2 += tv * Wd2[k * 3 + 2];
    }
    for (int off = 32; off; off >>= 1) {
        p0 += __shfl_down(p0, off);
        p1 += __shfl_down(p1, off);
        p2 += __shfl_down(p2, off);
    }
    if (lane == 0) {
        out[r * 3 + 0] = p0 + bd2[0];
        out[r * 3 + 1] = p1 + bd2[1];
        out[r * 3 + 2] = p2 + bd2[2];
    }
}

extern "C" void kernel_launch(void* const* d_in, const int* in_sizes, int n_in,
                              void* d_out, int out_size, void* d_ws, size_t ws_size,
                              hipStream_t stream) {
    const float* x = (const float*)d_in[0];
    const float* x_mask = (const float*)d_in[1];
    const float* edge_attr = (const float*)d_in[2];
    const float* W_e1 = (const float*)d_in[4];
    const float* b_e1 = (const float*)d_in[5];
    const float* W_e2 = (const float*)d_in[6];
    const float* b_e2 = (const float*)d_in[7];
    const float* W_m1 = (const float*)d_in[8];
    const float* b_m1 = (const float*)d_in[9];
    const float* W_m2 = (const float*)d_in[10];
    const float* b_m2 = (const float*)d_in[11];
    const float* W_u1 = (const float*)d_in[12];
    const float* b_u1 = (const float*)d_in[13];
    const float* W_u2 = (const float*)d_in[14];
    const float* b_u2 = (const float*)d_in[15];
    const float* W_d1 = (const float*)d_in[16];
    const float* b_d1 = (const float*)d_in[17];
    const float* W_d2 = (const float*)d_in[18];
    const float* b_d2 = (const float*)d_in[19];
    const int* edge_index = (const int*)d_in[20];
    const int* batch = (const int*)d_in[21];
    float* out = (float*)d_out;

    char* wp = (char*)d_ws;
    auto carve = [&](size_t bytes) {
        char* r = wp;
        wp += (bytes + 255) & ~(size_t)255;
        return r;
    };
    float* h = (float*)carve(sizeof(float) * (size_t)NN * 128);
    float* Ps = (float*)carve(sizeof(float) * (size_t)NN * 128);
    float* Pd = (float*)carve(sizeof(float) * (size_t)NN * 128);
    float* accm = (float*)carve(sizeof(float) * (size_t)NN * 128);
    float4* ea_s = (float4*)carve(sizeof(float4) * (size_t)EE);
    float* stats = (float*)carve(sizeof(float) * 4096);
    float* sum_h = stats;             // 1024
    float* sum_hbc = stats + 1024;    // 1024
    float* cnt_node = stats + 2048;   // 8
    float* cnt_bc = stats + 2056;     // 8
    float* gterm = stats + 2304;      // 1024
    int* deg = (int*)carve(sizeof(int) * NN);
    int* row_ptr = (int*)carve(sizeof(int) * (NN + 1));
    int* cursor = (int*)carve(sizeof(int) * NN);
    int* src_sorted = (int*)carve(sizeof(int) * EE);
    int* exbuf = (int*)carve(sizeof(int) * NN);
    int* blksum = (int*)carve(sizeof(int) * 256);
    // packed weights (bf16 hi/lo, [n][k])
    short* We2h = (short*)carve(sizeof(short) * 16384);
    short* We2l = (short*)carve(sizeof(short) * 16384);
    short* Wm1sh = (short*)carve(sizeof(short) * 16384);
    short* Wm1sl = (short*)carve(sizeof(short) * 16384);
    short* Wm1dh = (short*)carve(sizeof(short) * 16384);
    short* Wm1dl = (short*)carve(sizeof(short) * 16384);
    short* Wm2h = (short*)carve(sizeof(short) * 16384);
    short* Wm2l = (short*)carve(sizeof(short) * 16384);
    short* Wu1h = (short*)carve(sizeof(short) * 32768);
    short* Wu1l = (short*)carve(sizeof(short) * 32768);
    short* Wu2h = (short*)carve(sizeof(short) * 16384);
    short* Wu2l = (short*)carve(sizeof(short) * 16384);
    short* Wd1h = (short*)carve(sizeof(short) * 16384);
    short* Wd1l = (short*)carve(sizeof(short) * 16384);

    const dim3 b256(256);
    const int gE256 = (EE + 255) / 256;

    hipMemsetAsync(deg, 0, sizeof(int) * NN, stream);
    hipMemsetAsync(stats, 0, sizeof(float) * 2064, stream);
    // pack all weights to bf16 hi/lo MFMA-B layout
    k_pack_all<<<512, b256, 0, stream>>>(W_e2, W_m1, W_m2, W_u1, W_u2, W_d1,
                                         We2h, We2l, Wm1sh, Wm1sl, Wm1dh, Wm1dl,
                                         Wm2h, Wm2l, Wu1h, Wu1l, Wu2h, Wu2l, Wd1h, Wd1l);
    // CSR
    k_count<<<gE256, b256, 0, stream>>>(edge_index, deg);
    k_scan1<<<NBLK, b256, 0, stream>>>(deg, exbuf, blksum);
    k_scan2<<<1, b256, 0, stream>>>(blksum);
    k_scan3<<<NBLK, b256, 0, stream>>>(exbuf, blksum, row_ptr, cursor);
    k_scatter<<<gE256, b256, 0, stream>>>(edge_index, edge_attr, cursor, src_sorted, ea_s);
    // encoder
    k_enc1<<<(NN + 31) / 32, b256, 0, stream>>>(x, x_mask, W_e1, b_e1, accm, NN);
    mgemm<false, false, true, false, false, false, false><<<GB64, b256, 0, stream>>>(
        accm, nullptr, We2h, We2l, nullptr, nullptr, b_e2, nullptr, nullptr, nullptr, h, nullptr, nullptr, NN);
    // per-graph stats (once)
    k_stats_bc<<<GB64, b256, 0, stream>>>(h, x_mask, batch, sum_h, sum_hbc, cnt_node, cnt_bc);

    for (int rep = 0; rep < 3; ++rep) {
        k_gterm<<<GG, 128, 0, stream>>>(sum_h, sum_hbc, cnt_node, cnt_bc, W_u1, gterm);
        // Ps = h@W_m1[src]; Pd = h@W_m1[dst] + b_m1  (one pass over h)
        mgemm<false, false, false, false, false, false, true><<<GB64, b256, 0, stream>>>(
            h, nullptr, Wm1sh, Wm1sl, Wm1dh, Wm1dl, nullptr, b_m1, nullptr, nullptr, Ps, Pd, nullptr, NN);
        k_edge_agg<<<NN / 4, b256, 0, stream>>>(Ps, Pd, row_ptr, src_sorted, ea_s, W_m1, accm);
        // agg = accm @ W_m2 + b_m2 -> Ps
        mgemm<false, false, true, false, false, false, false><<<GB64, b256, 0, stream>>>(
            accm, nullptr, Wm2h, Wm2l, nullptr, nullptr, b_m2, nullptr, nullptr, nullptr, Ps, nullptr, nullptr, NN);
        // pre = relu([h|agg] @ Wu1[0:256] + gterm[batch] + b_u1) -> Pd
        mgemm<true, false, true, true, true, false, false><<<GB64, b256, 0, stream>>>(
            h, Ps, Wu1h, Wu1l, nullptr, nullptr, b_u1, nullptr, gterm, batch, Pd, nullptr, nullptr, NN);
        // h += pre @ Wu2 + bu2 (+ fused per-graph column sums for next rep)
        if (rep < 2) {
            hipMemsetAsync(sum_h, 0, sizeof(float) * 1024, stream);
            mgemm<false, true, true, false, false, true, false><<<GB64, b256, 0, stream>>>(
                Pd, nullptr, Wu2h, Wu2l, nullptr, nullptr, b_u2, nullptr, nullptr, batch, h, nullptr, sum_h, NN);
        } else {
            mgemm<false, true, true, false, false, false, false><<<GB64, b256, 0, stream>>>(
                Pd, nullptr, Wu2h, Wu2l, nullptr, nullptr, b_u2, nullptr, nullptr, batch, h, nullptr, nullptr, NN);
        }
    }
    // decoder
    mgemm<true, false, true, false, false, false, false><<<GB64, b256, 0, stream>>>(
        h, nullptr, Wd1h, Wd1l, nullptr, nullptr, b_d1, nullptr, nullptr, nullptr, accm, nullptr, nullptr, NN);
    k_dec2<<<NN / 4, b256, 0, stream>>>(accm, W_d2, b_d2, out, NN);
}